// Round 2
// baseline (294.058 us; speedup 1.0000x reference)
//
#include <hip/hip_runtime.h>

#define N_NODES 10000
#define N_EDGES 320000
#define N_PAIRS 2048
#define IN_CH 128
#define HIDDEN 512
#define PPB 8        // pairs per block in the fused pair kernel
#define MAXDEG 512   // LDS capacity for one adjacency list (Poisson(64) tail << 512)

// ---------------------------------------------------------------------------
// Workspace layout (ints):
//   deg    [0,      10000)
//   fill   [10000,  20000)
//   rowptr [20000,  30001)
//   adj    [30016,  30016+640000)
// total ~2.6 MB
// ---------------------------------------------------------------------------

__global__ void k_deg(const int* __restrict__ ei, int* __restrict__ deg) {
    int e = blockIdx.x * blockDim.x + threadIdx.x;
    if (e >= N_EDGES) return;
    int s = ei[e];
    int d = ei[N_EDGES + e];
    atomicAdd(&deg[s], 1);
    atomicAdd(&deg[d], 1);
}

// Single-block scan over 10000 degrees -> exclusive prefix (rowptr).
__global__ __launch_bounds__(1024) void k_scan(const int* __restrict__ deg,
                                               int* __restrict__ rowptr) {
    __shared__ int sc[1024];
    const int t = threadIdx.x;
    const int base = t * 10;
    int pref[10];
    int sum = 0;
#pragma unroll
    for (int k = 0; k < 10; ++k) {
        int idx = base + k;
        int d = (idx < N_NODES) ? deg[idx] : 0;
        pref[k] = sum;   // exclusive prefix within this thread's chunk
        sum += d;
    }
    sc[t] = sum;
    __syncthreads();
    // Hillis-Steele inclusive scan over 1024 partial sums
    for (int off = 1; off < 1024; off <<= 1) {
        int v = (t >= off) ? sc[t - off] : 0;
        __syncthreads();
        sc[t] += v;
        __syncthreads();
    }
    const int excl = sc[t] - sum;
#pragma unroll
    for (int k = 0; k < 10; ++k) {
        int idx = base + k;
        if (idx < N_NODES) rowptr[idx] = excl + pref[k];
    }
    if (t == 1023) rowptr[N_NODES] = sc[1023];
}

__global__ void k_scatter(const int* __restrict__ ei,
                          const int* __restrict__ rowptr,
                          int* __restrict__ fill,
                          int* __restrict__ adj) {
    int e = blockIdx.x * blockDim.x + threadIdx.x;
    if (e >= N_EDGES) return;
    int s = ei[e];
    int d = ei[N_EDGES + e];
    int p = atomicAdd(&fill[s], 1);
    adj[rowptr[s] + p] = d;
    p = atomicAdd(&fill[d], 1);
    adj[rowptr[d] + p] = s;
}

// Fused: xij, weighted common-neighbor embedding, 2-layer MLP, output.
// One block handles PPB pairs so W1 (512 KB) is re-read only 256x total.
__global__ __launch_bounds__(256) void k_pairs(
    const float* __restrict__ x,
    const int* __restrict__ tar,
    const int* __restrict__ rowptr,
    const int* __restrict__ adj,
    const float* __restrict__ W1,
    const float* __restrict__ b1,
    const float* __restrict__ W2,
    const float* __restrict__ b2,
    float* __restrict__ out) {
    __shared__ int adjJ[MAXDEG];
    __shared__ float xs[PPB][2 * IN_CH];
    __shared__ float red[PPB][4];
    const int tid = threadIdx.x;

    // ---- Phase 1: build xs = [xij | cn_emb] for PPB pairs ----
    for (int p = 0; p < PPB; ++p) {
        const int b = blockIdx.x * PPB + p;
        const int ti = tar[b];
        const int tj = tar[N_PAIRS + b];
        if (tid < IN_CH) {
            xs[p][tid] = x[ti * IN_CH + tid] * x[tj * IN_CH + tid];
            xs[p][IN_CH + tid] = 0.0f;
        }
        const int rj = rowptr[tj];
        const int dj = rowptr[tj + 1] - rj;
        const int djc = dj < MAXDEG ? dj : MAXDEG;
        for (int q = tid; q < djc; q += 256) adjJ[q] = adj[rj + q];
        __syncthreads();
        const int ri = rowptr[ti];
        const int di = rowptr[ti + 1] - ri;
        for (int pp = tid; pp < di; pp += 256) {
            const int u = adj[ri + pp];
            int cnt = 0;
            for (int q = 0; q < djc; ++q) cnt += (adjJ[q] == u) ? 1 : 0;
            for (int q = djc; q < dj; ++q) cnt += (adj[rj + q] == u) ? 1 : 0;
            if (cnt) {  // rare (~0.4 matches/pair): weighted by duplicate multiplicity
                const float fc = (float)cnt;
                const float* __restrict__ xu = x + (size_t)u * IN_CH;
                for (int d = 0; d < IN_CH; ++d)
                    atomicAdd(&xs[p][IN_CH + d], fc * xu[d]);
            }
        }
        __syncthreads();
    }

    // ---- Phase 2: MLP. Thread j owns hidden units j and j+256 for all PPB pairs ----
    float acc0[PPB], acc1[PPB];
#pragma unroll
    for (int p = 0; p < PPB; ++p) { acc0[p] = 0.0f; acc1[p] = 0.0f; }
    const int j = tid;
#pragma unroll 4
    for (int k = 0; k < 2 * IN_CH; ++k) {
        const float wa = W1[k * HIDDEN + j];
        const float wb = W1[k * HIDDEN + j + 256];
#pragma unroll
        for (int p = 0; p < PPB; ++p) {
            acc0[p] += xs[p][k] * wa;
            acc1[p] += xs[p][k] * wb;
        }
    }
    const float bja = b1[j], bjb = b1[j + 256];
    const float w2a = W2[j], w2b = W2[j + 256];
    const int lane = tid & 63;
    const int wid = tid >> 6;
#pragma unroll
    for (int p = 0; p < PPB; ++p) {
        float ha = acc0[p] + bja; ha = ha > 0.0f ? ha : 0.0f;
        float hb = acc1[p] + bjb; hb = hb > 0.0f ? hb : 0.0f;
        float part = ha * w2a + hb * w2b;
        for (int off = 32; off >= 1; off >>= 1)
            part += __shfl_down(part, off, 64);
        if (lane == 0) red[p][wid] = part;
    }
    __syncthreads();
    if (tid < PPB) {
        out[blockIdx.x * PPB + tid] =
            b2[0] + red[tid][0] + red[tid][1] + red[tid][2] + red[tid][3];
    }
}

extern "C" void kernel_launch(void* const* d_in, const int* in_sizes, int n_in,
                              void* d_out, int out_size, void* d_ws, size_t ws_size,
                              hipStream_t stream) {
    const float* x   = (const float*)d_in[0];
    const int*   ei  = (const int*)d_in[1];
    const int*   tar = (const int*)d_in[2];
    const float* W1  = (const float*)d_in[3];
    const float* b1  = (const float*)d_in[4];
    const float* W2  = (const float*)d_in[5];
    const float* b2  = (const float*)d_in[6];
    float* out = (float*)d_out;

    int* ws     = (int*)d_ws;
    int* deg    = ws;          // 10000
    int* fill   = ws + 10000;  // 10000
    int* rowptr = ws + 20000;  // 10001
    int* adj    = ws + 30016;  // 640000

    hipMemsetAsync(deg, 0, 20000 * sizeof(int), stream);  // zero deg + fill
    k_deg<<<(N_EDGES + 255) / 256, 256, 0, stream>>>(ei, deg);
    k_scan<<<1, 1024, 0, stream>>>(deg, rowptr);
    k_scatter<<<(N_EDGES + 255) / 256, 256, 0, stream>>>(ei, rowptr, fill, adj);
    k_pairs<<<N_PAIRS / PPB, 256, 0, stream>>>(x, tar, rowptr, adj, W1, b1, W2, b2, out);
}

// Round 3
// 135.512 us; speedup vs baseline: 2.1700x; 2.1700x over previous
//
#include <hip/hip_runtime.h>

#define N_NODES 10000
#define N_EDGES 320000
#define N_PAIRS 2048
#define IN_CH 128
#define HIDDEN 512
#define PPB 8
#define WIDTH 160   // fixed adjacency row width; max degree ~ Binom(640K,1e-4): 64+12sigma << 160

// ---------------------------------------------------------------------------
// Workspace layout (int units):
//   cnt  [0, 10000)
//   adjF [10240, 10240 + 10000*160)          = [10240, 1610240)
//   xs   [1610240, 1610240 + 2048*256 floats) ~ 8.2 MB total
// ---------------------------------------------------------------------------

// One-pass CSR-ish build: fixed-width rows, no scan needed.
__global__ void k_build(const int* __restrict__ ei, int* __restrict__ cnt,
                        int* __restrict__ adjF) {
    int e = blockIdx.x * blockDim.x + threadIdx.x;
    if (e >= N_EDGES) return;
    int s = ei[e];
    int d = ei[N_EDGES + e];
    int p = atomicAdd(&cnt[s], 1);
    if (p < WIDTH) adjF[s * WIDTH + p] = d;
    p = atomicAdd(&cnt[d], 1);
    if (p < WIDTH) adjF[d * WIDTH + p] = s;
}

// One wave per pair: build xs[b] = [xij (128) | cn_emb (128)].
// Matches (rare, ~0.4/pair) are processed wave-parallel via ballot+broadcast.
__global__ __launch_bounds__(64) void k_inter(
    const float* __restrict__ x,
    const int* __restrict__ tar,
    const int* __restrict__ cnt,
    const int* __restrict__ adjF,
    float* __restrict__ xs) {
    __shared__ int adjJ[WIDTH];
    const int b = blockIdx.x;
    const int t = threadIdx.x;
    const int ti = tar[b];
    const int tj = tar[N_PAIRS + b];
    int cj = cnt[tj]; cj = cj < WIDTH ? cj : WIDTH;
    int ci = cnt[ti]; ci = ci < WIDTH ? ci : WIDTH;
    for (int q = t; q < cj; q += 64) adjJ[q] = adjF[tj * WIDTH + q];
    __syncthreads();

    float c0 = 0.0f, c1 = 0.0f;  // cn_emb dims t and t+64 (register-resident)
    const int cir = (ci + 63) & ~63;
    for (int pp = t; pp < cir; pp += 64) {
        const int u = (pp < ci) ? adjF[ti * WIDTH + pp] : -1;
        int cm = 0;
        for (int q = 0; q < cj; ++q) cm += (adjJ[q] == u) ? 1 : 0;
        unsigned long long m = __ballot(cm > 0);
        while (m) {
            const int lane = __ffsll(m) - 1;
            m &= m - 1;
            const int uu = __shfl(u, lane, 64);
            const float fc = (float)__shfl(cm, lane, 64);
            c0 += fc * x[uu * IN_CH + t];
            c1 += fc * x[uu * IN_CH + 64 + t];
        }
    }

    const float xi0 = x[ti * IN_CH + t], xi1 = x[ti * IN_CH + 64 + t];
    const float xj0 = x[tj * IN_CH + t], xj1 = x[tj * IN_CH + 64 + t];
    float* __restrict__ row = xs + (size_t)b * (2 * IN_CH);
    row[t]       = xi0 * xj0;
    row[64 + t]  = xi1 * xj1;
    row[128 + t] = c0;
    row[192 + t] = c1;
}

// MLP: 8 pairs per block; thread j owns hidden units j and j+256.
__global__ __launch_bounds__(256) void k_mlp(
    const float* __restrict__ xs,
    const float* __restrict__ W1,
    const float* __restrict__ b1,
    const float* __restrict__ W2,
    const float* __restrict__ b2,
    float* __restrict__ out) {
    __shared__ float sxs[PPB][2 * IN_CH];
    __shared__ float red[PPB][4];
    const int tid = threadIdx.x;
    const int base = blockIdx.x * PPB;
#pragma unroll
    for (int r = 0; r < PPB; ++r) sxs[r][tid] = xs[(size_t)(base + r) * 256 + tid];
    const float bja = b1[tid], bjb = b1[tid + 256];
    const float w2a = W2[tid], w2b = W2[tid + 256];
    __syncthreads();

    float acc0[PPB], acc1[PPB];
#pragma unroll
    for (int p = 0; p < PPB; ++p) { acc0[p] = 0.0f; acc1[p] = 0.0f; }
#pragma unroll 8
    for (int k = 0; k < 2 * IN_CH; ++k) {
        const float wa = W1[k * HIDDEN + tid];
        const float wb = W1[k * HIDDEN + tid + 256];
#pragma unroll
        for (int p = 0; p < PPB; ++p) {
            acc0[p] = fmaf(sxs[p][k], wa, acc0[p]);
            acc1[p] = fmaf(sxs[p][k], wb, acc1[p]);
        }
    }

    const int lane = tid & 63;
    const int wid = tid >> 6;
#pragma unroll
    for (int p = 0; p < PPB; ++p) {
        float ha = acc0[p] + bja; ha = ha > 0.0f ? ha : 0.0f;
        float hb = acc1[p] + bjb; hb = hb > 0.0f ? hb : 0.0f;
        float part = ha * w2a + hb * w2b;
        for (int off = 32; off >= 1; off >>= 1)
            part += __shfl_down(part, off, 64);
        if (lane == 0) red[p][wid] = part;
    }
    __syncthreads();
    if (tid < PPB) {
        out[base + tid] = b2[0] + red[tid][0] + red[tid][1] + red[tid][2] + red[tid][3];
    }
}

extern "C" void kernel_launch(void* const* d_in, const int* in_sizes, int n_in,
                              void* d_out, int out_size, void* d_ws, size_t ws_size,
                              hipStream_t stream) {
    const float* x   = (const float*)d_in[0];
    const int*   ei  = (const int*)d_in[1];
    const int*   tar = (const int*)d_in[2];
    const float* W1  = (const float*)d_in[3];
    const float* b1  = (const float*)d_in[4];
    const float* W2  = (const float*)d_in[5];
    const float* b2  = (const float*)d_in[6];
    float* out = (float*)d_out;

    int* ws   = (int*)d_ws;
    int* cnt  = ws;            // 10000
    int* adjF = ws + 10240;    // 1,600,000
    float* xs = (float*)(ws + 1610240);  // 2048*256 floats

    hipMemsetAsync(cnt, 0, N_NODES * sizeof(int), stream);
    k_build<<<(N_EDGES + 255) / 256, 256, 0, stream>>>(ei, cnt, adjF);
    k_inter<<<N_PAIRS, 64, 0, stream>>>(x, tar, cnt, adjF, xs);
    k_mlp<<<N_PAIRS / PPB, 256, 0, stream>>>(xs, W1, b1, W2, b2, out);
}

// Round 4
// 119.703 us; speedup vs baseline: 2.4566x; 1.1321x over previous
//
#include <hip/hip_runtime.h>

#define N_NODES 10000
#define N_EDGES 320000
#define N_PAIRS 2048
#define IN_CH 128
#define HIDDEN 512
#define PPB 8
#define WIDTH 160        // max degree ~Binom(640K,1e-4) ≈ 64±8, max≈104 << 160
#define NSLOT 4096       // one slot per tar entry (canonical slot via atomicCAS)

// ---------------------------------------------------------------------------
// Workspace layout (int units):
//   slotmap [0, 10240)            node -> canonical tar slot, -1 if not target
//   cnt     [10240, 14336)        per-slot fill count
//   adjC    [14336, 342016)       ushort[NSLOT][WIDTH] compact adjacency (1.3 MB, L2-resident)
//   xs      [342016, 866304)      float[2048][256]
// ---------------------------------------------------------------------------

__global__ void k_map(const int* __restrict__ tar, int* __restrict__ slotmap,
                      int* __restrict__ cnt) {
    int t = blockIdx.x * blockDim.x + threadIdx.x;
    if (t >= NSLOT) return;
    cnt[t] = 0;
    int v = tar[t];
    atomicCAS(&slotmap[v], -1, t);   // first writer wins; any canonical slot is fine
}

__global__ void k_edges(const int* __restrict__ ei,
                        const int* __restrict__ slotmap,
                        int* __restrict__ cnt,
                        unsigned short* __restrict__ adjC) {
    int e = blockIdx.x * blockDim.x + threadIdx.x;
    if (e >= N_EDGES) return;
    int s = ei[e];
    int d = ei[N_EDGES + e];
    int sl = slotmap[s];
    if (sl >= 0) {
        int p = atomicAdd(&cnt[sl], 1);
        if (p < WIDTH) adjC[sl * WIDTH + p] = (unsigned short)d;
    }
    sl = slotmap[d];
    if (sl >= 0) {
        int p = atomicAdd(&cnt[sl], 1);
        if (p < WIDTH) adjC[sl * WIDTH + p] = (unsigned short)s;
    }
}

// One wave per pair: xs[b] = [xij (128) | cn_emb (128)].
// Matches (~0.4/pair) processed wave-parallel via ballot+broadcast.
__global__ __launch_bounds__(64) void k_inter(
    const float* __restrict__ x,
    const int* __restrict__ tar,
    const int* __restrict__ slotmap,
    const int* __restrict__ cnt,
    const unsigned short* __restrict__ adjC,
    float* __restrict__ xs) {
    __shared__ unsigned short adjJ[WIDTH];
    const int b = blockIdx.x;
    const int t = threadIdx.x;
    const int ti = tar[b];
    const int tj = tar[N_PAIRS + b];
    const int si = slotmap[ti];
    const int sj = slotmap[tj];
    int cj = cnt[sj]; cj = cj < WIDTH ? cj : WIDTH;
    int ci = cnt[si]; ci = ci < WIDTH ? ci : WIDTH;
    for (int q = t; q < cj; q += 64) adjJ[q] = adjC[sj * WIDTH + q];
    __syncthreads();

    float c0 = 0.0f, c1 = 0.0f;  // cn_emb dims t and t+64
    const int cir = (ci + 63) & ~63;
    for (int pp = t; pp < cir; pp += 64) {
        const int u = (pp < ci) ? (int)adjC[si * WIDTH + pp] : 0xFFFF;
        int cm = 0;
        for (int q = 0; q < cj; ++q) cm += ((int)adjJ[q] == u) ? 1 : 0;
        unsigned long long m = __ballot(cm > 0);
        while (m) {
            const int lane = __ffsll(m) - 1;
            m &= m - 1;
            const int uu = __shfl(u, lane, 64);
            const float fc = (float)__shfl(cm, lane, 64);
            c0 += fc * x[uu * IN_CH + t];
            c1 += fc * x[uu * IN_CH + 64 + t];
        }
    }

    const float xi0 = x[ti * IN_CH + t], xi1 = x[ti * IN_CH + 64 + t];
    const float xj0 = x[tj * IN_CH + t], xj1 = x[tj * IN_CH + 64 + t];
    float* __restrict__ row = xs + (size_t)b * (2 * IN_CH);
    row[t]       = xi0 * xj0;
    row[64 + t]  = xi1 * xj1;
    row[128 + t] = c0;
    row[192 + t] = c1;
}

// MLP: 8 pairs per block; thread j owns hidden units j and j+256.
__global__ __launch_bounds__(256) void k_mlp(
    const float* __restrict__ xs,
    const float* __restrict__ W1,
    const float* __restrict__ b1,
    const float* __restrict__ W2,
    const float* __restrict__ b2,
    float* __restrict__ out) {
    __shared__ float sxs[PPB][2 * IN_CH];
    __shared__ float red[PPB][4];
    const int tid = threadIdx.x;
    const int base = blockIdx.x * PPB;
#pragma unroll
    for (int r = 0; r < PPB; ++r) sxs[r][tid] = xs[(size_t)(base + r) * 256 + tid];
    const float bja = b1[tid], bjb = b1[tid + 256];
    const float w2a = W2[tid], w2b = W2[tid + 256];
    __syncthreads();

    float acc0[PPB], acc1[PPB];
#pragma unroll
    for (int p = 0; p < PPB; ++p) { acc0[p] = 0.0f; acc1[p] = 0.0f; }
#pragma unroll 8
    for (int k = 0; k < 2 * IN_CH; ++k) {
        const float wa = W1[k * HIDDEN + tid];
        const float wb = W1[k * HIDDEN + tid + 256];
#pragma unroll
        for (int p = 0; p < PPB; ++p) {
            acc0[p] = fmaf(sxs[p][k], wa, acc0[p]);
            acc1[p] = fmaf(sxs[p][k], wb, acc1[p]);
        }
    }

    const int lane = tid & 63;
    const int wid = tid >> 6;
#pragma unroll
    for (int p = 0; p < PPB; ++p) {
        float ha = acc0[p] + bja; ha = ha > 0.0f ? ha : 0.0f;
        float hb = acc1[p] + bjb; hb = hb > 0.0f ? hb : 0.0f;
        float part = ha * w2a + hb * w2b;
        for (int off = 32; off >= 1; off >>= 1)
            part += __shfl_down(part, off, 64);
        if (lane == 0) red[p][wid] = part;
    }
    __syncthreads();
    if (tid < PPB) {
        out[base + tid] = b2[0] + red[tid][0] + red[tid][1] + red[tid][2] + red[tid][3];
    }
}

extern "C" void kernel_launch(void* const* d_in, const int* in_sizes, int n_in,
                              void* d_out, int out_size, void* d_ws, size_t ws_size,
                              hipStream_t stream) {
    const float* x   = (const float*)d_in[0];
    const int*   ei  = (const int*)d_in[1];
    const int*   tar = (const int*)d_in[2];
    const float* W1  = (const float*)d_in[3];
    const float* b1  = (const float*)d_in[4];
    const float* W2  = (const float*)d_in[5];
    const float* b2  = (const float*)d_in[6];
    float* out = (float*)d_out;

    int* ws = (int*)d_ws;
    int* slotmap          = ws;                 // 10240
    int* cnt              = ws + 10240;         // 4096
    unsigned short* adjC  = (unsigned short*)(ws + 14336);  // 4096*160 ushort
    float* xs             = (float*)(ws + 342016);          // 2048*256 float

    hipMemsetAsync(slotmap, 0xFF, 10240 * sizeof(int), stream);  // -1
    k_map<<<NSLOT / 256, 256, 0, stream>>>(tar, slotmap, cnt);
    k_edges<<<(N_EDGES + 255) / 256, 256, 0, stream>>>(ei, slotmap, cnt, adjC);
    k_inter<<<N_PAIRS, 64, 0, stream>>>(x, tar, slotmap, cnt, adjC, xs);
    k_mlp<<<N_PAIRS / PPB, 256, 0, stream>>>(xs, W1, b1, W2, b2, out);
}